// Round 1
// 926.992 us; speedup vs baseline: 1.2432x; 1.2432x over previous
//
#include <hip/hip_runtime.h>
#include <hip/hip_bf16.h>

typedef unsigned short u16;
typedef unsigned int u32;
typedef unsigned char u8;
typedef __attribute__((ext_vector_type(4))) float f32x4;
typedef __attribute__((ext_vector_type(8))) short s16x8;

#define HG_N   200000
#define HG_E   50000
#define HG_NNZ 2000000
#define HG_F   256
#define HG_D   128

// ---- binned CSR build geometry ----
#define NB     256            // buckets per direction (one pass2 block per bucket)
#define CHUNK  8192           // pairs per pass1 block
#define CAP    10240          // per-bucket capacity in binned scratch (mean 7812, sigma 88)
#define SPAN_E 196            // ceil(HG_E / NB)
#define SPAN_V 782            // ceil(HG_N / NB)

__device__ __forceinline__ u32 f2bf_rne(float x) {
  u32 u = __float_as_uint(x);
  return (u + 0x7fffu + ((u >> 16) & 1u)) >> 16;
}
__device__ __forceinline__ float bf2f(u32 bits) { return __uint_as_float(bits << 16); }
__device__ __forceinline__ float bf_lo(u32 u) { return __uint_as_float(u << 16); }
__device__ __forceinline__ float bf_hi(u32 u) { return __uint_as_float(u & 0xffff0000u); }

// ---------------- dtype detection ----------------
__global__ void detect_dtype(const u16* __restrict__ f, int* __restrict__ flag) {
  __shared__ int acc[4];
  int t = threadIdx.x;
  int bad = 0;
  for (int i = t; i < 2048; i += 256) {
    u32 u = f[2 * i];
    int e = (u >> 7) & 0xff;
    if (e < 0x70 || e > 0x88) bad++;
  }
#pragma unroll
  for (int off = 32; off; off >>= 1) bad += __shfl_down(bad, off);
  if ((t & 63) == 0) acc[t >> 6] = bad;
  __syncthreads();
  if (t == 0) flag[0] = (acc[0] + acc[1] + acc[2] + acc[3] > 200) ? 1 : 0;
}

// ---------------- CSR build: bucket-binned two-pass scatter ----------------
// Pass 1: partition pairs into NB buckets by destination-segment id, with LDS
// staging so the binned array is written in coalesced ~256B runs (the old
// direct scatter paid ~8x write amplification: 4M scattered 8B stores each
// dirtied a 64B line -> 250MB WRITE_SIZE).
// Record packing: x = col | (local_seg_id << 18)  (col < 2^18, local < 2^10),
//                 y = fp32 weight bits (bit-exact).

template <int DIR>
__global__ __launch_bounds__(256) void bin_pass1(
    const int* __restrict__ pv, const int* __restrict__ pe,
    const void* __restrict__ wve, const void* __restrict__ wev,
    const int* __restrict__ flag,
    int2* __restrict__ binned,      // this direction's scratch: NB*CAP entries
    int* __restrict__ gcur) {       // this direction's NB bucket cursors (zeroed)
  constexpr int SPAN = DIR ? SPAN_V : SPAN_E;
  __shared__ int cnt[NB], lbase[NB], run[NB], gbase[NB], sc[NB];
  __shared__ int2 stage[CHUNK];     // 64 KB, records sorted by bucket
  __shared__ u8 sb[CHUNK];          // bucket id per staged record
  int t = threadIdx.x;
  int base = blockIdx.x * CHUNK;
  int n = HG_NNZ - base; if (n > CHUNK) n = CHUNK;

  cnt[t] = 0;
  __syncthreads();

  const int* key = DIR ? pv : pe;   // segment id (destination)
  const int* col = DIR ? pe : pv;   // gather column
  const float* wf = (const float*)(DIR ? wev : wve);
  const u16* wh = (const u16*)(DIR ? wev : wve);
  int fp32 = *flag;

  // sweep 1: LDS histogram of buckets
#pragma unroll 4
  for (int k = 0; k < CHUNK / 256; ++k) {
    int p = base + k * 256 + t;
    if (p < HG_NNZ) atomicAdd(&cnt[key[p] / SPAN], 1);
  }
  __syncthreads();

  // exclusive block scan of cnt -> lbase
  sc[t] = cnt[t];
  __syncthreads();
  for (int off = 1; off < NB; off <<= 1) {
    int x = (t >= off) ? sc[t - off] : 0;
    __syncthreads();
    sc[t] += x;
    __syncthreads();
  }
  lbase[t] = sc[t] - cnt[t];
  run[t] = lbase[t];
  // reserve this block's run range in each bucket (one global atomic per bucket)
  gbase[t] = atomicAdd(&gcur[t], cnt[t]);
  __syncthreads();

  // sweep 2: rank + stage records into LDS (bucket-sorted)
#pragma unroll 4
  for (int k = 0; k < CHUNK / 256; ++k) {
    int p = base + k * 256 + t;
    if (p < HG_NNZ) {
      int kk = key[p];
      int b = kk / SPAN;
      int local = kk - b * SPAN;
      float w = fp32 ? wf[p] : bf2f(wh[p]);
      int s = atomicAdd(&run[b], 1);
      int2 r; r.x = col[p] | (local << 18); r.y = __float_as_int(w);
      stage[s] = r;
      sb[s] = (u8)b;
    }
  }
  __syncthreads();

  // write-out: LDS is bucket-sorted, so consecutive lanes write consecutive
  // global slots within each bucket run -> coalesced
  for (int i = t; i < n; i += 256) {
    int bb = sb[i];
    int d = gbase[bb] + (i - lbase[bb]);
    if (d < CAP) binned[(size_t)bb * CAP + d] = stage[i];
  }
}

// Pass 2: one block per bucket. Block exclusively owns its segment range and
// its ~64KB slice of the final entry array -> all scattered writes stay in one
// XCD's L2 and write back ~1x. Also derives rp[] for its range (replaces the
// global hist + 3-kernel scan pipeline).
template <int DIR>
__global__ __launch_bounds__(256) void csr_pass2(
    const int2* __restrict__ binned, const int* __restrict__ gcur,
    int* __restrict__ rp, int2* __restrict__ ent) {
  constexpr int SPAN = DIR ? SPAN_V : SPAN_E;
  constexpr int K = DIR ? HG_N : HG_E;
  __shared__ int cc[NB], sc[NB];
  __shared__ int lcnt[1024], lrp[1024];
  int t = threadIdx.x;
  int b = blockIdx.x;

  // scan bucket totals to get this bucket's global CSR base
  cc[t] = gcur[t];
  __syncthreads();
  sc[t] = cc[t];
  __syncthreads();
  for (int off = 1; off < NB; off <<= 1) {
    int x = (t >= off) ? sc[t - off] : 0;
    __syncthreads();
    sc[t] += x;
    __syncthreads();
  }
  int gb = sc[b] - cc[b];
  int total = cc[b]; if (total > CAP) total = CAP;

  for (int j = t; j < 1024; j += 256) lcnt[j] = 0;
  __syncthreads();

  int kb = b * SPAN;
  int span_act = K - kb; if (span_act > SPAN) span_act = SPAN;
  const int2* rec = binned + (size_t)b * CAP;

  // local histogram over this bucket's segments
#pragma unroll 4
  for (int i = t; i < total; i += 256) atomicAdd(&lcnt[rec[i].x >> 18], 1);
  __syncthreads();

  // exclusive scan of lcnt[0..1024) -> lrp (4 elems per thread + block scan)
  int vals[4], s0 = 0;
#pragma unroll
  for (int j = 0; j < 4; ++j) { vals[j] = lcnt[t * 4 + j]; s0 += vals[j]; }
  sc[t] = s0;
  __syncthreads();
  for (int off = 1; off < NB; off <<= 1) {
    int x = (t >= off) ? sc[t - off] : 0;
    __syncthreads();
    sc[t] += x;
    __syncthreads();
  }
  int running = sc[t] - s0;
#pragma unroll
  for (int j = 0; j < 4; ++j) { lrp[t * 4 + j] = running; running += vals[j]; }
  __syncthreads();

  // emit row pointers for this range (boundary entries written consistently
  // by both neighboring blocks; last block writes rp[K] = NNZ)
  for (int j = t; j <= span_act; j += 256) rp[kb + j] = gb + lrp[j];
  __syncthreads();

  // scatter into the final CSR slice; atomicAdd on lrp returns base+rank
#pragma unroll 4
  for (int i = t; i < total; i += 256) {
    int2 r = rec[i];
    int local = r.x >> 18;
    int slot = gb + atomicAdd(&lrp[local], 1);
    int2 o; o.x = r.x & 0x3FFFF; o.y = r.y;
    ent[slot] = o;
  }
}

// ---------------- GEMM: x = feats @ W + b (bf16 MFMA, bf16 out) ----------------

__global__ void transpose_w_kernel(const void* __restrict__ W, u16* __restrict__ WT,
                                   const int* __restrict__ flag) {
  int idx = blockIdx.x * 256 + threadIdx.x;  // 256*128 = 32768 elems
  u16 v = (*flag) ? (u16)f2bf_rne(((const float*)W)[idx]) : ((const u16*)W)[idx];
  WT[(idx & 127) * 256 + (idx >> 7)] = v;
}

template <bool FP32>
__global__ __launch_bounds__(256) void gemm_kernel(
    const void* __restrict__ A,    // feats [N][256] (bf16 or fp32 per flag)
    const u16* __restrict__ WT,    // bf16 [128][256] (W transposed, canonical)
    const void* __restrict__ bias, // [128]
    const int* __restrict__ flag,
    u16* __restrict__ xb) {        // bf16 [N][128]
  if ((*flag != 0) != FP32) return;
  __shared__ u16 wt[32768];
  {
    const uint4* src = (const uint4*)WT;  // 4096 granules, 32 per row
    uint4* d = (uint4*)wt;
    for (int i = threadIdx.x; i < 4096; i += 256) {
      int r = i >> 5, g = i & 31;
      d[(r << 5) | (g ^ (r & 31))] = src[i];
    }
  }
  __syncthreads();
  int lane = threadIdx.x & 63;
  int q = lane >> 4, m = lane & 15;
  int wave0 = blockIdx.x * 4 + (threadIdx.x >> 6);
  int nwaves = gridDim.x * 4;
  const s16x8* wlds = (const s16x8*)wt;
  for (int strip = wave0; strip < HG_N / 16; strip += nwaves) {
    f32x4 acc[8];
#pragma unroll
    for (int n = 0; n < 8; ++n) acc[n] = (f32x4){0.f, 0.f, 0.f, 0.f};
#pragma unroll
    for (int k0 = 0; k0 < 8; ++k0) {
      s16x8 a;
      if (FP32) {
        const float* ar = (const float*)A + (size_t)(strip * 16 + m) * 256 + q * 8 + k0 * 32;
        float4 p0 = *(const float4*)ar;
        float4 p1 = *(const float4*)(ar + 4);
        a[0] = (short)f2bf_rne(p0.x); a[1] = (short)f2bf_rne(p0.y);
        a[2] = (short)f2bf_rne(p0.z); a[3] = (short)f2bf_rne(p0.w);
        a[4] = (short)f2bf_rne(p1.x); a[5] = (short)f2bf_rne(p1.y);
        a[6] = (short)f2bf_rne(p1.z); a[7] = (short)f2bf_rne(p1.w);
      } else {
        a = *(const s16x8*)((const u16*)A + (size_t)(strip * 16 + m) * 256 + q * 8 + k0 * 32);
      }
      int g = (k0 << 2) | q;
#pragma unroll
      for (int n = 0; n < 8; ++n) {
        int rr = n * 16 + m;  // B col index; WT row
        s16x8 b = wlds[(rr << 5) | (g ^ (rr & 31))];  // B[k0*32+q*8+j][rr]
        acc[n] = __builtin_amdgcn_mfma_f32_16x16x32_bf16(a, b, acc[n], 0, 0, 0);
      }
    }
#pragma unroll
    for (int n = 0; n < 8; ++n) {
      float bv = FP32 ? ((const float*)bias)[n * 16 + m] : bf2f(((const u16*)bias)[n * 16 + m]);
#pragma unroll
      for (int r = 0; r < 4; ++r) {
        // C/D layout: col = lane&15, row = (lane>>4)*4 + r  [m89/m91 verified]
        xb[(size_t)(strip * 16 + q * 4 + r) * 128 + n * 16 + m] = (u16)f2bf_rne(acc[n][r] + bv);
      }
    }
  }
}

// ---------------- Pull aggregation over bf16 rows, fp32 accumulate ----------------

__global__ __launch_bounds__(256) void pull_kernel(
    const int* __restrict__ rp, const int2* __restrict__ ent,
    const u32* __restrict__ src, u32* __restrict__ dst, int nrows) {
  int row = blockIdx.x * 4 + (threadIdx.x >> 6);
  if (row >= nrows) return;
  int lane = threadIdx.x & 63;
  int beg = rp[row], end = rp[row + 1];
  float ax = 0.f, ay = 0.f, den = 0.f;
  int j = beg;
  for (; j + 4 <= end; j += 4) {
    int2 e0 = ent[j], e1 = ent[j + 1], e2 = ent[j + 2], e3 = ent[j + 3];
    u32 u0 = src[(size_t)e0.x * 64 + lane];
    u32 u1 = src[(size_t)e1.x * 64 + lane];
    u32 u2 = src[(size_t)e2.x * 64 + lane];
    u32 u3 = src[(size_t)e3.x * 64 + lane];
    float w0 = __int_as_float(e0.y), w1 = __int_as_float(e1.y);
    float w2 = __int_as_float(e2.y), w3 = __int_as_float(e3.y);
    den += (w0 + w1) + (w2 + w3);
    ax = fmaf(w0, bf_lo(u0), ax); ay = fmaf(w0, bf_hi(u0), ay);
    ax = fmaf(w1, bf_lo(u1), ax); ay = fmaf(w1, bf_hi(u1), ay);
    ax = fmaf(w2, bf_lo(u2), ax); ay = fmaf(w2, bf_hi(u2), ay);
    ax = fmaf(w3, bf_lo(u3), ax); ay = fmaf(w3, bf_hi(u3), ay);
  }
  for (; j < end; ++j) {
    int2 e0 = ent[j];
    u32 u0 = src[(size_t)e0.x * 64 + lane];
    float w0 = __int_as_float(e0.y);
    den += w0;
    ax = fmaf(w0, bf_lo(u0), ax);
    ay = fmaf(w0, bf_hi(u0), ay);
  }
  float inv = 1.0f / fmaxf(den, 1e-12f);
  dst[(size_t)row * 64 + lane] = f2bf_rne(ax * inv) | (f2bf_rne(ay * inv) << 16);
}

// ---------------- Softmax (bf16 in, bf16/fp32 out) ----------------

template <bool FP32>
__global__ __launch_bounds__(256) void softmax_kernel(const u32* __restrict__ xb,
                                                      void* __restrict__ out,
                                                      const int* __restrict__ flag) {
  if ((*flag != 0) != FP32) return;
  int row = blockIdx.x * 4 + (threadIdx.x >> 6);
  int lane = threadIdx.x & 63;
  u32 u = xb[(size_t)row * 64 + lane];
  float v0 = __uint_as_float(u << 16);
  float v1 = __uint_as_float(u & 0xffff0000u);
  float mx = fmaxf(v0, v1);
#pragma unroll
  for (int off = 32; off; off >>= 1) mx = fmaxf(mx, __shfl_xor(mx, off));
  float e0 = __expf(v0 - mx), e1 = __expf(v1 - mx);
  float s = e0 + e1;
#pragma unroll
  for (int off = 32; off; off >>= 1) s += __shfl_xor(s, off);
  float inv = 1.0f / s;
  if (FP32) {
    float2 o; o.x = e0 * inv; o.y = e1 * inv;
    ((float2*)out)[(size_t)row * 64 + lane] = o;
  } else {
    ((u32*)out)[(size_t)row * 64 + lane] = f2bf_rne(e0 * inv) | (f2bf_rne(e1 * inv) << 16);
  }
}

// ---------------- launch ----------------

extern "C" void kernel_launch(void* const* d_in, const int* in_sizes, int n_in,
                              void* d_out, int out_size, void* d_ws, size_t ws_size,
                              hipStream_t stream) {
  const void* feats = d_in[0];
  const void* W = d_in[1];
  const void* bias = d_in[2];
  const void* wve = d_in[3];
  const void* wev = d_in[4];
  const int* pv = (const int*)d_in[5];
  const int* pe = (const int*)d_in[6];

  char* p = (char*)d_ws;
  auto alloc = [&](size_t b) { char* r = p; p += (b + 255) & ~(size_t)255; return r; };
  int* flag = (int*)alloc(4);
  // big region: binned scratch (41.9MB, used only during CSR build) aliases
  // xb (51.2MB) + yb (12.8MB), which are first written by the GEMM afterwards.
  char* big = alloc(64000000);
  u16* xb = (u16*)big;                          // bf16 [N][128]
  u16* yb = (u16*)(big + 51200000);             // bf16 [E][128]
  int2* binned0 = (int2*)big;                   // NB*CAP edge-dir records
  int2* binned1 = binned0 + (size_t)NB * CAP;   // NB*CAP vertex-dir records
  u16* wtg = (u16*)alloc(HG_D * HG_F * 2);      // canonical W^T bf16
  int* rpe = (int*)alloc((HG_E + 1) * 4);
  int* rpv = (int*)alloc((HG_N + 1) * 4);
  int2* ente = (int2*)alloc((size_t)HG_NNZ * 8);
  int2* entv = (int2*)alloc((size_t)HG_NNZ * 8);
  int* gcur = (int*)alloc(2 * NB * 4);
  // total ~97 MB

  detect_dtype<<<1, 256, 0, stream>>>((const u16*)feats, flag);

  // CSR build: bin -> per-bucket scatter (hist/scan pipeline folded into pass2)
  hipMemsetAsync(gcur, 0, 2 * NB * 4, stream);
  int nb1 = (HG_NNZ + CHUNK - 1) / CHUNK;
  bin_pass1<0><<<nb1, 256, 0, stream>>>(pv, pe, wve, wev, flag, binned0, gcur);
  bin_pass1<1><<<nb1, 256, 0, stream>>>(pv, pe, wve, wev, flag, binned1, gcur + NB);
  csr_pass2<0><<<NB, 256, 0, stream>>>(binned0, gcur, rpe, ente);
  csr_pass2<1><<<NB, 256, 0, stream>>>(binned1, gcur + NB, rpv, entv);

  // x = feats @ W + b
  transpose_w_kernel<<<128, 256, 0, stream>>>(W, wtg, flag);
  gemm_kernel<false><<<1024, 256, 0, stream>>>(feats, wtg, bias, flag, xb);
  gemm_kernel<true><<<1024, 256, 0, stream>>>(feats, wtg, bias, flag, xb);

  // two hops of weighted-mean aggregation (xb and yb ping-pong)
  pull_kernel<<<HG_E / 4, 256, 0, stream>>>(rpe, ente, (const u32*)xb, (u32*)yb, HG_E);
  pull_kernel<<<HG_N / 4, 256, 0, stream>>>(rpv, entv, (const u32*)yb, (u32*)xb, HG_N);
  pull_kernel<<<HG_E / 4, 256, 0, stream>>>(rpe, ente, (const u32*)xb, (u32*)yb, HG_E);
  pull_kernel<<<HG_N / 4, 256, 0, stream>>>(rpv, entv, (const u32*)yb, (u32*)xb, HG_N);

  softmax_kernel<false><<<HG_N / 4, 256, 0, stream>>>((const u32*)xb, d_out, flag);
  softmax_kernel<true><<<HG_N / 4, 256, 0, stream>>>((const u32*)xb, d_out, flag);
}